// Round 11
// baseline (126.686 us; speedup 1.0000x reference)
//
#include <hip/hip_runtime.h>
#include <stdint.h>

#define DIN 128
#define DOUT 128
#define LN_EPS 1e-5f
#define CAPX 64  // per-XCD bucket capacity (safe even if all edges land on one XCD)
#define NXCD 8

// s_getreg hwreg encoding: id | offset<<6 | (width-1)<<11 ; HW_REG_XCC_ID = 20
#define XCC_ID_ENC (20 | (0 << 6) | ((4 - 1) << 11))

typedef __attribute__((ext_vector_type(8))) short bf16x8;
typedef __attribute__((ext_vector_type(4))) float f32x4;

__device__ __forceinline__ unsigned short f2bf(float f) {
  uint32_t u = __float_as_uint(f);
  uint32_t r = (u + 0x7fffu + ((u >> 16) & 1u)) >> 16;
  return (unsigned short)r;
}
__device__ __forceinline__ float bf2f(uint32_t lo16) {
  return __uint_as_float(lo16 << 16);
}
__device__ __forceinline__ uint32_t pack2(unsigned short a, unsigned short b) {
  return (uint32_t)a | ((uint32_t)b << 16);
}
// packed f32x2 -> bf16x2 (RNE), low = lo
__device__ __forceinline__ uint32_t cvtpk_bf16(float lo, float hi) {
  uint32_t r;
  asm volatile("v_cvt_pk_bf16_f32 %0, %1, %2" : "=v"(r) : "v"(lo), "v"(hi));
  return r;
}

// ---------------------------------------------------------------------------
// FAT slim kernel: blocks < wblk -> weight image prep; blocks >= wblk -> zero
// deg8 (int4 stores). Weight image (transposed bf16, XOR-swizzled LDS image):
//   [0, 32768):       We^T [c<128][k<128], row stride 256 B
//   [32768, 98304):   W1^T [c<128][k<256], row stride 512 B
//   [98304, 131072):  W2^T [c<128][k<128], row stride 256 B
// swizzle: byte_in_row = (k*2) ^ ((c&7)<<4)
// ---------------------------------------------------------------------------
__global__ __launch_bounds__(256) void k_prep(
    const float* __restrict__ We, const float* __restrict__ W1,
    const float* __restrict__ W2, char* __restrict__ img,
    int4* __restrict__ degv4, int nv4, int wblk) {
  if (blockIdx.x >= wblk) {  // ---- zero deg8 ----
    int i = (blockIdx.x - wblk) * 256 + threadIdx.x;
    if (i < nv4) degv4[i] = make_int4(0, 0, 0, 0);
    return;
  }
  int tid = blockIdx.x * 256 + threadIdx.x;
  const int total = 128 * 128 + 256 * 128 + 128 * 128;  // 65536
  for (int i = tid; i < total; i += wblk * 256) {
    int off;
    float v;
    if (i < 16384) {
      int k = i >> 7, c = i & 127;
      v = We[k * 128 + c];
      off = c * 256 + ((k * 2) ^ ((c & 7) << 4));
    } else if (i < 49152) {
      int j = i - 16384;
      int k = j >> 7, c = j & 127;
      v = W1[k * 128 + c];
      off = 32768 + c * 512 + ((k * 2) ^ ((c & 7) << 4));
    } else {
      int j = i - 49152;
      int k = j >> 7, c = j & 127;
      v = W2[k * 128 + c];
      off = 98304 + c * 256 + ((k * 2) ^ ((c & 7) << 4));
    }
    *(unsigned short*)(img + off) = f2bf(v);
  }
}

// ---------------------------------------------------------------------------
// FAT kernel: blocks < eblk  -> hist+place with XCD-LOCAL atomics:
//   xcc = s_getreg(XCC_ID)&7; r = wg-scope atomicAdd(&deg8[xcc*N+d],1);
//   ssrc8[xcc][d][r] = (u16)src
//   Per-XCD copies are only ever touched by their own XCD's L2, so
//   workgroup-scope (local-L2, no fabric round trip) atomicity suffices;
//   kernel-end release flushes L2s (same mechanism R10's stores relied on).
//   Max over the partition is order/mapping-invariant -> deterministic.
// blocks >= eblk -> GEMM: P16 = bf16(vf @ We), vf16 = bf16(vf)
//   BM=256 (4 waves x 4 m-tiles), We in LDS, A-frags from global.
// ---------------------------------------------------------------------------
__global__ __launch_bounds__(256, 1) void k_gemm_histplace(
    const float* __restrict__ vf, const char* __restrict__ wimg,
    short* __restrict__ P16, short* __restrict__ vf16, int N,
    const int* __restrict__ ei, int* __restrict__ deg8,
    unsigned short* __restrict__ ssrc8, int E, int eblk) {
  __shared__ char Wet[32768];
  if (blockIdx.x < eblk) {  // ---- hist + place (XCD-local) ----
    int e = blockIdx.x * 256 + threadIdx.x;
    if (e < E) {
      int s = ei[e];
      int d = ei[E + e];
      uint32_t xcc = ((uint32_t)__builtin_amdgcn_s_getreg(XCC_ID_ENC)) & (NXCD - 1);
      int r = __hip_atomic_fetch_add(&deg8[(size_t)xcc * N + d], 1,
                                     __ATOMIC_RELAXED, __HIP_MEMORY_SCOPE_WORKGROUP);
      if (r < CAPX)
        ssrc8[((size_t)xcc * N + d) * CAPX + r] = (unsigned short)s;
    }
    return;
  }
  // ---- GEMM ----
  int bid = blockIdx.x - eblk;
  {
    const uint4* src = (const uint4*)wimg;
    for (int i = threadIdx.x; i < 2048; i += 256) *(uint4*)(Wet + i * 16) = src[i];
  }
  int wave = threadIdx.x >> 6, lane = threadIdx.x & 63;
  int l15 = lane & 15, lq = lane >> 4;
  int row0 = bid * 256 + wave * 64;
  int rs[4];
#pragma unroll
  for (int m = 0; m < 4; ++m) rs[m] = min(row0 + m * 16 + l15, N - 1);

  f32x4 acc[4][8];
#pragma unroll
  for (int m = 0; m < 4; ++m)
#pragma unroll
    for (int n = 0; n < 8; ++n) acc[m][n] = (f32x4)0.f;

  float4 pf0[4], pf1[4];
#pragma unroll
  for (int m = 0; m < 4; ++m) {
    const float* p = vf + (size_t)rs[m] * DIN + lq * 8;
    pf0[m] = *(const float4*)p;
    pf1[m] = *(const float4*)(p + 4);
  }
  __syncthreads();

#pragma unroll
  for (int ks = 0; ks < 4; ++ks) {
    bf16x8 afr[4];
#pragma unroll
    for (int m = 0; m < 4; ++m) {
      uint4 st;
      st.x = cvtpk_bf16(pf0[m].x, pf0[m].y);
      st.y = cvtpk_bf16(pf0[m].z, pf0[m].w);
      st.z = cvtpk_bf16(pf1[m].x, pf1[m].y);
      st.w = cvtpk_bf16(pf1[m].z, pf1[m].w);
      afr[m] = *(bf16x8*)&st;
      int row = row0 + m * 16 + l15;
      if (row < N)
        *(uint4*)(vf16 + (size_t)row * DIN + ks * 32 + lq * 8) = st;
    }
    if (ks < 3) {
#pragma unroll
      for (int m = 0; m < 4; ++m) {
        const float* p = vf + (size_t)rs[m] * DIN + (ks + 1) * 32 + lq * 8;
        pf0[m] = *(const float4*)p;
        pf1[m] = *(const float4*)(p + 4);
      }
    }
    int kb = ks * 64 + lq * 16;
#pragma unroll
    for (int n = 0; n < 8; ++n) {
      int c = n * 16 + l15;
      bf16x8 b = *(const bf16x8*)(Wet + c * 256 + (kb ^ ((c & 7) << 4)));
#pragma unroll
      for (int m = 0; m < 4; ++m)
        acc[m][n] = __builtin_amdgcn_mfma_f32_16x16x32_bf16(afr[m], b, acc[m][n], 0, 0, 0);
    }
  }
#pragma unroll
  for (int m = 0; m < 4; ++m) {
    int rbase = row0 + m * 16 + lq * 4;
#pragma unroll
    for (int n = 0; n < 8; ++n) {
      int col = n * 16 + l15;
#pragma unroll
      for (int reg = 0; reg < 4; ++reg) {
        int row = rbase + reg;
        if (row < N) P16[(size_t)row * DOUT + col] = (short)f2bf(acc[m][n][reg]);
      }
    }
  }
}

// ---------------------------------------------------------------------------
// A16[v] = total>0 ? bf16(max over 8 XCD sublists of P[src] - P[v] + b_edge) : 0
// 16-lane groups (uint4 = 8 bf16/lane = full 256B row), 4 vertices per wave.
// ---------------------------------------------------------------------------
__global__ __launch_bounds__(256) void k_segmax(const short* __restrict__ P16,
                                                const int* __restrict__ deg8,
                                                const unsigned short* __restrict__ ssrc8,
                                                const float* __restrict__ b_edge,
                                                short* __restrict__ A16, int N) {
  int lane = threadIdx.x & 63;
  int l16 = lane & 15;
  int v = blockIdx.x * 16 + (threadIdx.x >> 4);
  if (v >= N) return;
  // lane x<8 holds this vertex's count in XCD copy x
  int cx = (l16 < NXCD) ? deg8[(size_t)l16 * N + v] : 0;
  float m[8];
#pragma unroll
  for (int j = 0; j < 8; ++j) m[j] = -__builtin_inff();
  int total = 0;
  for (int x = 0; x < NXCD; ++x) {
    int cnt = min(__shfl(cx, (lane & 48) + x, 64), CAPX);
    total += cnt;
    size_t base = ((size_t)x * N + v) * CAPX;
    for (int r = 0; r < cnt; r += 16) {
      int c2 = min(16, cnt - r);
      int sv = (l16 < c2) ? (int)ssrc8[base + r + l16] : 0;
#pragma unroll 2
      for (int i = 0; i < c2; ++i) {
        int s = __shfl(sv, (lane & 48) + i, 64);
        uint4 p = *(const uint4*)(P16 + (size_t)s * DOUT + l16 * 8);
        m[0] = fmaxf(m[0], bf2f(p.x & 0xffffu));
        m[1] = fmaxf(m[1], bf2f(p.x >> 16));
        m[2] = fmaxf(m[2], bf2f(p.y & 0xffffu));
        m[3] = fmaxf(m[3], bf2f(p.y >> 16));
        m[4] = fmaxf(m[4], bf2f(p.z & 0xffffu));
        m[5] = fmaxf(m[5], bf2f(p.z >> 16));
        m[6] = fmaxf(m[6], bf2f(p.w & 0xffffu));
        m[7] = fmaxf(m[7], bf2f(p.w >> 16));
      }
    }
  }
  uint4 pv = *(const uint4*)(P16 + (size_t)v * DOUT + l16 * 8);
  float4 be0 = *(const float4*)(b_edge + l16 * 8);
  float4 be1 = *(const float4*)(b_edge + l16 * 8 + 4);
  float pvf[8] = {bf2f(pv.x & 0xffffu), bf2f(pv.x >> 16), bf2f(pv.y & 0xffffu),
                  bf2f(pv.y >> 16),     bf2f(pv.z & 0xffffu), bf2f(pv.z >> 16),
                  bf2f(pv.w & 0xffffu), bf2f(pv.w >> 16)};
  float bev[8] = {be0.x, be0.y, be0.z, be0.w, be1.x, be1.y, be1.z, be1.w};
  uint32_t o[4];
#pragma unroll
  for (int j = 0; j < 4; ++j) {
    float a0 = (total > 0) ? (m[2 * j] - pvf[2 * j] + bev[2 * j]) : 0.f;
    float a1 = (total > 0) ? (m[2 * j + 1] - pvf[2 * j + 1] + bev[2 * j + 1]) : 0.f;
    o[j] = pack2(f2bf(a0), f2bf(a1));
  }
  *(uint4*)(A16 + (size_t)v * DOUT + l16 * 8) = *(uint4*)o;
}

// ---------------------------------------------------------------------------
// out = relu(LN(concat(vf16,A16) @ W1 + b1)) @ W2 + b2
// BM=256 (4 waves x 4 m-tiles). LDS: W1t 64K (aliased by Hs after GEMM1) +
// W2t 32K = 96K. A-frags direct from global.
// ---------------------------------------------------------------------------
__global__ __launch_bounds__(256, 1) void k_mlp12(
    const short* __restrict__ vf16, const short* __restrict__ A16,
    const char* __restrict__ wimg, const float* __restrict__ b1,
    const float* __restrict__ gamma, const float* __restrict__ beta,
    const float* __restrict__ b2, float* __restrict__ out, int N) {
  __shared__ char lds[98304];
  char* W1t = lds;          // 64K; reused as Hs (256 rows x 256 B) after GEMM1
  char* W2t = lds + 65536;  // 32K
  {
    const uint4* src = (const uint4*)(wimg + 32768);
    for (int i = threadIdx.x; i < 6144; i += 256) *(uint4*)(lds + i * 16) = src[i];
  }
  int wave = threadIdx.x >> 6, lane = threadIdx.x & 63;
  int l15 = lane & 15, lq = lane >> 4;
  int row0 = blockIdx.x * 256 + wave * 64;
  int rs[4];
#pragma unroll
  for (int m = 0; m < 4; ++m) rs[m] = min(row0 + m * 16 + l15, N - 1);
  float b1v[8], gv[8], bev[8], b2v[8];
#pragma unroll
  for (int n = 0; n < 8; ++n) {
    int c = n * 16 + l15;
    b1v[n] = b1[c];
    gv[n] = gamma[c];
    bev[n] = beta[c];
    b2v[n] = b2[c];
  }
  f32x4 acc[4][8];
#pragma unroll
  for (int m = 0; m < 4; ++m)
#pragma unroll
    for (int n = 0; n < 8; ++n) acc[m][n] = (f32x4)0.f;

  uint4 pa[4];
#pragma unroll
  for (int m = 0; m < 4; ++m)
    pa[m] = *(const uint4*)(vf16 + (size_t)rs[m] * DIN + lq * 8);
  __syncthreads();

  // GEMM1: X = concat(vf16, A16) [256 k], W1t in LDS
#pragma unroll
  for (int ks = 0; ks < 8; ++ks) {
    bf16x8 afr[4];
#pragma unroll
    for (int m = 0; m < 4; ++m) afr[m] = *(bf16x8*)&pa[m];
    if (ks < 7) {
      int ks1 = ks + 1;
      const short* srcb = (ks1 < 4) ? vf16 : A16;
      int chunk = (ks1 < 4) ? ks1 : ks1 - 4;
#pragma unroll
      for (int m = 0; m < 4; ++m)
        pa[m] = *(const uint4*)(srcb + (size_t)rs[m] * DIN + chunk * 32 + lq * 8);
    }
    int kb = ks * 64 + lq * 16;
#pragma unroll
    for (int n = 0; n < 8; ++n) {
      int c = n * 16 + l15;
      bf16x8 b = *(const bf16x8*)(W1t + c * 512 + (kb ^ ((c & 7) << 4)));
#pragma unroll
      for (int m = 0; m < 4; ++m)
        acc[m][n] = __builtin_amdgcn_mfma_f32_16x16x32_bf16(afr[m], b, acc[m][n], 0, 0, 0);
    }
  }
  __syncthreads();  // all W1t reads complete before Hs overwrites

  // bias + LayerNorm + relu -> Hs (aliases W1t)
#pragma unroll
  for (int m = 0; m < 4; ++m) {
#pragma unroll
    for (int n = 0; n < 8; ++n)
#pragma unroll
      for (int reg = 0; reg < 4; ++reg) acc[m][n][reg] += b1v[n];
    float s[4], sq[4];
#pragma unroll
    for (int reg = 0; reg < 4; ++reg) {
      s[reg] = 0.f;
      sq[reg] = 0.f;
#pragma unroll
      for (int n = 0; n < 8; ++n) {
        float h = acc[m][n][reg];
        s[reg] += h;
        sq[reg] += h * h;
      }
    }
#pragma unroll
    for (int mm = 1; mm < 16; mm <<= 1) {
#pragma unroll
      for (int reg = 0; reg < 4; ++reg) {
        s[reg] += __shfl_xor(s[reg], mm, 64);
        sq[reg] += __shfl_xor(sq[reg], mm, 64);
      }
    }
#pragma unroll
    for (int reg = 0; reg < 4; ++reg) {
      float mu = s[reg] * (1.f / 128.f);
      float var = sq[reg] * (1.f / 128.f) - mu * mu;
      float rsn = rsqrtf(var + LN_EPS);
      int rr = wave * 64 + m * 16 + lq * 4 + reg;  // local row in block
#pragma unroll
      for (int n = 0; n < 8; ++n) {
        float o = fmaxf(fmaf((acc[m][n][reg] - mu) * rsn, gv[n], bev[n]), 0.f);
        int c = n * 16 + l15;
        *(unsigned short*)(W1t + rr * 256 + ((c * 2) ^ ((rr & 7) << 4))) = f2bf(o);
      }
    }
  }
  __syncthreads();

  // GEMM2: Hs @ W2t
  f32x4 acc2[4][8];
#pragma unroll
  for (int m = 0; m < 4; ++m)
#pragma unroll
    for (int n = 0; n < 8; ++n) acc2[m][n] = (f32x4)0.f;
#pragma unroll
  for (int ks = 0; ks < 4; ++ks) {
    int kb = ks * 64 + lq * 16;
    bf16x8 a2[4];
#pragma unroll
    for (int m = 0; m < 4; ++m) {
      int rr = wave * 64 + m * 16 + l15;
      a2[m] = *(const bf16x8*)(W1t + rr * 256 + (kb ^ ((rr & 7) << 4)));
    }
#pragma unroll
    for (int n = 0; n < 8; ++n) {
      int c = n * 16 + l15;
      bf16x8 b = *(const bf16x8*)(W2t + c * 256 + (kb ^ ((c & 7) << 4)));
#pragma unroll
      for (int m = 0; m < 4; ++m)
        acc2[m][n] = __builtin_amdgcn_mfma_f32_16x16x32_bf16(a2[m], b, acc2[m][n], 0, 0, 0);
    }
  }
#pragma unroll
  for (int m = 0; m < 4; ++m) {
    int rbase = row0 + m * 16 + lq * 4;
#pragma unroll
    for (int n = 0; n < 8; ++n) {
      int col = n * 16 + l15;
#pragma unroll
      for (int reg = 0; reg < 4; ++reg) {
        int row = rbase + reg;
        if (row < N) out[(size_t)row * DOUT + col] = acc2[m][n][reg] + b2v[n];
      }
    }
  }
}

extern "C" void kernel_launch(void* const* d_in, const int* in_sizes, int n_in,
                              void* d_out, int out_size, void* d_ws, size_t ws_size,
                              hipStream_t stream) {
  const float* vf     = (const float*)d_in[0];
  const int*   ei     = (const int*)d_in[1];
  const float* W_edge = (const float*)d_in[2];
  const float* b_edge = (const float*)d_in[3];
  const float* W1     = (const float*)d_in[4];
  const float* b1     = (const float*)d_in[5];
  const float* gamma  = (const float*)d_in[6];
  const float* beta   = (const float*)d_in[7];
  const float* W2     = (const float*)d_in[8];
  const float* b2     = (const float*)d_in[9];
  float* out = (float*)d_out;

  int N = in_sizes[0] / DIN;
  int E = in_sizes[1] / 2;
  int nblk = (N + 255) / 256;
  int eblk = (E + 255) / 256;

  char* ws = (char*)d_ws;
  size_t seg16 = (size_t)N * DOUT * sizeof(short);  // 12.8 MB
  short* P16  = (short*)ws;
  short* vf16 = (short*)(ws + seg16);
  short* A16  = (short*)(ws + 2 * seg16);
  char*  wimg = ws + 3 * seg16;                        // 131072 B
  int*   deg8 = (int*)(ws + 3 * seg16 + 131072);       // NXCD*N ints
  unsigned short* ssrc8 =
      (unsigned short*)(deg8 + (((size_t)NXCD * N + 3) & ~(size_t)3));  // NXCD*N*CAPX u16

  int nv4 = (NXCD * N + 3) / 4;  // int4s of deg8 to zero
  int zblk = (nv4 + 255) / 256;
  k_prep<<<64 + zblk, 256, 0, stream>>>(W_edge, W1, W2, wimg, (int4*)deg8, nv4, 64);
  k_gemm_histplace<<<eblk + nblk, 256, 0, stream>>>(vf, wimg, P16, vf16, N, ei,
                                                    deg8, ssrc8, E, eblk);
  k_segmax<<<(N + 15) / 16, 256, 0, stream>>>(P16, deg8, ssrc8, b_edge, A16, N);
  k_mlp12<<<nblk, 256, 0, stream>>>(vf16, A16, wimg, b1, gamma, beta, b2, out, N);
}